// Round 3
// baseline (153.217 us; speedup 1.0000x reference)
//
#include <hip/hip_runtime.h>

#define IH 4096
#define IW 4096
#define KH 16
#define KW 16
#define OH 4081
#define OW 4081

#define TBR 64       // output rows per block
#define TBC 256      // output cols per block
#define LROWS 79     // TBR + 15
#define LCH 40       // 16B chunks per LDS row (34 logical + xor headroom)
#define LSTR (LCH*8) // 320 shorts per row

typedef short bf16x8 __attribute__((ext_vector_type(8)));
typedef float f32x16 __attribute__((ext_vector_type(16)));

static __device__ __forceinline__ unsigned int f2bf(float f) {
    unsigned int u = __float_as_uint(f);
    return (u + 0x7FFFu + ((u >> 16) & 1u)) >> 16;   // RTNE
}

// Bt[(u*32 + n)*48 + vp] = w[u][vp - n] if 0 <= vp-n < 16 else 0   (48 KB)
__global__ void build_B(const float* __restrict__ wgt, unsigned short* __restrict__ Bt) {
    int idx = blockIdx.x * 256 + threadIdx.x;        // 0..24575
    if (idx >= 16 * 32 * 48) return;
    int vp = idx % 48;
    int n  = (idx / 48) & 31;
    int u  = idx / (48 * 32);
    int t  = vp - n;
    float val = (t >= 0 && t < KW) ? wgt[u * KW + t] : 0.0f;
    Bt[idx] = (unsigned short)f2bf(val);
}

__global__ __launch_bounds__(256, 3)
void conv_mfma32(const float* __restrict__ x,
                 const unsigned short* __restrict__ Bt,
                 const float* __restrict__ bias,
                 float* __restrict__ out) {
    __shared__ unsigned short tile[LROWS * LSTR];    // 50560 B

    const int tid  = threadIdx.x;
    const int lane = tid & 63;
    const int wv   = tid >> 6;       // 0..3
    const int rb   = wv >> 1;        // wave row-block 0..1 (32 rows each)
    const int cb   = wv & 1;         // wave col-block 0..1 (128 cols each)
    const int m    = lane & 31;      // A row m / B col n / C col
    const int hi   = lane >> 5;      // k-half select
    const int gy0  = blockIdx.y * TBR;
    const int gx0  = blockIdx.x * TBC;

    // ---- stage 79 x 272 fp32 -> bf16 LDS, xor-swizzled chunks ----
    for (int idx = tid; idx < LROWS * 68; idx += 256) {
        int row = idx / 68;
        int c   = idx - row * 68;    // float4 index, col = 4c
        int gy  = gy0 + row;
        int gx  = gx0 + 4 * c;
        float4 q = make_float4(0.f, 0.f, 0.f, 0.f);
        if (gy < IH && gx < IW) {    // IW % 4 == 0 -> float4 fully in or out
            q = *reinterpret_cast<const float4*>(x + (size_t)gy * IW + gx);
        }
        uint2 p;
        p.x = f2bf(q.x) | (f2bf(q.y) << 16);
        p.y = f2bf(q.z) | (f2bf(q.w) << 16);
        int s    = (row ^ (row >> 3)) & 7;
        int phys = (c >> 1) ^ s;
        *reinterpret_cast<uint2*>(&tile[row * LSTR + phys * 8 + (c & 1) * 4]) = p;
    }
    __syncthreads();

    // ---- main: wave = 32 rows x 4 col-groups(32) ; K=48 band per u ----
    f32x16 acc0 = {0,0,0,0,0,0,0,0,0,0,0,0,0,0,0,0};
    f32x16 acc1 = {0,0,0,0,0,0,0,0,0,0,0,0,0,0,0,0};
    f32x16 acc2 = {0,0,0,0,0,0,0,0,0,0,0,0,0,0,0,0};
    f32x16 acc3 = {0,0,0,0,0,0,0,0,0,0,0,0,0,0,0,0};

    const int cB = cb * 16 + hi;                     // logical chunk base per lane
    const unsigned short* Blane = Bt + m * 48 + hi * 8;

#pragma unroll
    for (int u = 0; u < KH; ++u) {
        const int rowA = rb * 32 + m + u;            // 0..78
        const int s    = (rowA ^ (rowA >> 3)) & 7;
        const unsigned short* rbase = &tile[rowA * LSTR];

        bf16x8 a[9];
#pragma unroll
        for (int d = 0; d < 9; ++d) {
            int phys = (cB + 2 * d) ^ s;
            a[d] = *reinterpret_cast<const bf16x8*>(rbase + phys * 8);
        }
        const unsigned short* Bu = Blane + u * (32 * 48);
        bf16x8 b0 = *reinterpret_cast<const bf16x8*>(Bu + 0);
        bf16x8 b1 = *reinterpret_cast<const bf16x8*>(Bu + 16);
        bf16x8 b2 = *reinterpret_cast<const bf16x8*>(Bu + 32);

        acc0 = __builtin_amdgcn_mfma_f32_32x32x16_bf16(a[0], b0, acc0, 0, 0, 0);
        acc0 = __builtin_amdgcn_mfma_f32_32x32x16_bf16(a[1], b1, acc0, 0, 0, 0);
        acc0 = __builtin_amdgcn_mfma_f32_32x32x16_bf16(a[2], b2, acc0, 0, 0, 0);
        acc1 = __builtin_amdgcn_mfma_f32_32x32x16_bf16(a[2], b0, acc1, 0, 0, 0);
        acc1 = __builtin_amdgcn_mfma_f32_32x32x16_bf16(a[3], b1, acc1, 0, 0, 0);
        acc1 = __builtin_amdgcn_mfma_f32_32x32x16_bf16(a[4], b2, acc1, 0, 0, 0);
        acc2 = __builtin_amdgcn_mfma_f32_32x32x16_bf16(a[4], b0, acc2, 0, 0, 0);
        acc2 = __builtin_amdgcn_mfma_f32_32x32x16_bf16(a[5], b1, acc2, 0, 0, 0);
        acc2 = __builtin_amdgcn_mfma_f32_32x32x16_bf16(a[6], b2, acc2, 0, 0, 0);
        acc3 = __builtin_amdgcn_mfma_f32_32x32x16_bf16(a[6], b0, acc3, 0, 0, 0);
        acc3 = __builtin_amdgcn_mfma_f32_32x32x16_bf16(a[7], b1, acc3, 0, 0, 0);
        acc3 = __builtin_amdgcn_mfma_f32_32x32x16_bf16(a[8], b2, acc3, 0, 0, 0);
    }

    // ---- epilogue: C/D col=lane&31, row=(reg&3)+8*(reg>>2)+4*hi ----
    const float bv   = bias[0];
    const int   row0 = gy0 + rb * 32 + 4 * hi;
    const int   col0 = gx0 + cb * 128 + m;
    const bool  full = (gy0 + TBR <= OH) && (gx0 + TBC <= OW);

    const f32x16* accs[4] = {&acc0, &acc1, &acc2, &acc3};
#pragma unroll
    for (int g = 0; g < 4; ++g) {
        const f32x16 acc = *accs[g];
        const int col = col0 + g * 32;
        float* op = out + col;
        if (full) {
#pragma unroll
            for (int r = 0; r < 16; ++r) {
                int rr = row0 + (r & 3) + 8 * (r >> 2);
                op[(size_t)rr * OW] = acc[r] + bv;
            }
        } else if (col < OW) {
#pragma unroll
            for (int r = 0; r < 16; ++r) {
                int rr = row0 + (r & 3) + 8 * (r >> 2);
                if (rr < OH) op[(size_t)rr * OW] = acc[r] + bv;
            }
        }
    }
}

extern "C" void kernel_launch(void* const* d_in, const int* in_sizes, int n_in,
                              void* d_out, int out_size, void* d_ws, size_t ws_size,
                              hipStream_t stream) {
    const float* x  = (const float*)d_in[0];
    const float* w  = (const float*)d_in[1];
    const float* b  = (const float*)d_in[2];
    float* out = (float*)d_out;
    unsigned short* Bt = (unsigned short*)d_ws;

    build_B<<<96, 256, 0, stream>>>(w, Bt);

    dim3 grid((OW + TBC - 1) / TBC, (OH + TBR - 1) / TBR);  // 16 x 64
    conv_mfma32<<<grid, dim3(256), 0, stream>>>(x, Bt, b, out);
}

// Round 4
// 137.734 us; speedup vs baseline: 1.1124x; 1.1124x over previous
//
#include <hip/hip_runtime.h>

#define IH 4096
#define IW 4096
#define KH 16
#define KW 16
#define OH 4081
#define OW 4081

#define TBR 64       // output rows per block
#define TBC 256      // output cols per block
#define LROWS 79     // TBR + 15
#define LCH 40       // 16B chunks per LDS row (34 logical + xor headroom)
#define LSTR (LCH*8) // 320 shorts per row (640 B = 0 mod 128 -> swizzle spreads banks)

typedef short bf16x8 __attribute__((ext_vector_type(8)));
typedef float f32x16 __attribute__((ext_vector_type(16)));

static __device__ __forceinline__ unsigned int f2bf(float f) {
    unsigned int u = __float_as_uint(f);
    return (u + 0x7FFFu + ((u >> 16) & 1u)) >> 16;   // RTNE
}

// Bt[(u*32 + n)*48 + vp] = w[u][vp - n] if 0 <= vp-n < 16 else 0   (48 KB)
__global__ void build_B(const float* __restrict__ wgt, unsigned short* __restrict__ Bt) {
    int idx = blockIdx.x * 256 + threadIdx.x;        // 0..24575
    if (idx >= 16 * 32 * 48) return;
    int vp = idx % 48;
    int n  = (idx / 48) & 31;
    int u  = idx / (48 * 32);
    int t  = vp - n;
    float val = (t >= 0 && t < KW) ? wgt[u * KW + t] : 0.0f;
    Bt[idx] = (unsigned short)f2bf(val);
}

__global__ __launch_bounds__(256, 3)
void conv_mfma32(const float* __restrict__ x,
                 const unsigned short* __restrict__ Bt,
                 const float* __restrict__ bias,
                 float* __restrict__ out) {
    __shared__ unsigned short tile[LROWS * LSTR];    // 50560 B

    const int tid  = threadIdx.x;
    const int lane = tid & 63;
    const int wv   = tid >> 6;       // 0..3
    const int rb   = wv >> 1;        // wave row-block 0..1 (32 rows each)
    const int cb   = wv & 1;         // wave col-block 0..1 (128 cols each)
    const int m    = lane & 31;      // A row m / B col n / C col
    const int hi   = lane >> 5;      // k-half select
    const int gy0  = blockIdx.y * TBR;
    const int gx0  = blockIdx.x * TBC;

    // ---- stage 79 x 272 fp32 -> bf16 LDS, one b128 write per 8 cols ----
    for (int idx = tid; idx < LROWS * 34; idx += 256) {
        int row = idx / 34;
        int c   = idx - row * 34;    // 8-col chunk index
        int gy  = gy0 + row;
        int gx  = gx0 + 8 * c;
        float4 q0 = make_float4(0.f, 0.f, 0.f, 0.f);
        float4 q1 = q0;
        if (gy < IH && gx < IW) {    // gx%8==0, IW%8==0 -> both halves in-bounds
            q0 = *reinterpret_cast<const float4*>(x + (size_t)gy * IW + gx);
            q1 = *reinterpret_cast<const float4*>(x + (size_t)gy * IW + gx + 4);
        }
        uint4 p;
        p.x = f2bf(q0.x) | (f2bf(q0.y) << 16);
        p.y = f2bf(q0.z) | (f2bf(q0.w) << 16);
        p.z = f2bf(q1.x) | (f2bf(q1.y) << 16);
        p.w = f2bf(q1.z) | (f2bf(q1.w) << 16);
        int s    = (row ^ (row >> 3)) & 7;
        int phys = c ^ s;
        *reinterpret_cast<uint4*>(&tile[row * LSTR + phys * 8]) = p;
    }
    __syncthreads();

    // ---- main: wave = 32 rows x 4 col-groups(32) ; K=48 band per u ----
    f32x16 acc0 = {0,0,0,0,0,0,0,0,0,0,0,0,0,0,0,0};
    f32x16 acc1 = {0,0,0,0,0,0,0,0,0,0,0,0,0,0,0,0};
    f32x16 acc2 = {0,0,0,0,0,0,0,0,0,0,0,0,0,0,0,0};
    f32x16 acc3 = {0,0,0,0,0,0,0,0,0,0,0,0,0,0,0,0};

    const int cB = cb * 16 + hi;                     // logical chunk base per lane
    const unsigned short* Blane = Bt + m * 48 + hi * 8;

    // B double-buffer in registers: prefetch distance 1 over the u-loop
    bf16x8 bc0 = *reinterpret_cast<const bf16x8*>(Blane + 0);
    bf16x8 bc1 = *reinterpret_cast<const bf16x8*>(Blane + 16);
    bf16x8 bc2 = *reinterpret_cast<const bf16x8*>(Blane + 32);

#pragma unroll
    for (int u = 0; u < KH; ++u) {
        // prefetch B[u+1] first: ~9 LDS reads + 12 MFMAs sit between issue and use
        bf16x8 bn0 = bc0, bn1 = bc1, bn2 = bc2;
        if (u + 1 < KH) {
            const unsigned short* Bu = Blane + (u + 1) * (32 * 48);
            bn0 = *reinterpret_cast<const bf16x8*>(Bu + 0);
            bn1 = *reinterpret_cast<const bf16x8*>(Bu + 16);
            bn2 = *reinterpret_cast<const bf16x8*>(Bu + 32);
        }

        const int rowA = rb * 32 + m + u;            // 0..78
        const int s    = (rowA ^ (rowA >> 3)) & 7;
        const unsigned short* rbase = &tile[rowA * LSTR];

        bf16x8 a[9];
#pragma unroll
        for (int d = 0; d < 9; ++d) {
            int phys = (cB + 2 * d) ^ s;
            a[d] = *reinterpret_cast<const bf16x8*>(rbase + phys * 8);
        }

        acc0 = __builtin_amdgcn_mfma_f32_32x32x16_bf16(a[0], bc0, acc0, 0, 0, 0);
        acc0 = __builtin_amdgcn_mfma_f32_32x32x16_bf16(a[1], bc1, acc0, 0, 0, 0);
        acc0 = __builtin_amdgcn_mfma_f32_32x32x16_bf16(a[2], bc2, acc0, 0, 0, 0);
        acc1 = __builtin_amdgcn_mfma_f32_32x32x16_bf16(a[2], bc0, acc1, 0, 0, 0);
        acc1 = __builtin_amdgcn_mfma_f32_32x32x16_bf16(a[3], bc1, acc1, 0, 0, 0);
        acc1 = __builtin_amdgcn_mfma_f32_32x32x16_bf16(a[4], bc2, acc1, 0, 0, 0);
        acc2 = __builtin_amdgcn_mfma_f32_32x32x16_bf16(a[4], bc0, acc2, 0, 0, 0);
        acc2 = __builtin_amdgcn_mfma_f32_32x32x16_bf16(a[5], bc1, acc2, 0, 0, 0);
        acc2 = __builtin_amdgcn_mfma_f32_32x32x16_bf16(a[6], bc2, acc2, 0, 0, 0);
        acc3 = __builtin_amdgcn_mfma_f32_32x32x16_bf16(a[6], bc0, acc3, 0, 0, 0);
        acc3 = __builtin_amdgcn_mfma_f32_32x32x16_bf16(a[7], bc1, acc3, 0, 0, 0);
        acc3 = __builtin_amdgcn_mfma_f32_32x32x16_bf16(a[8], bc2, acc3, 0, 0, 0);

        bc0 = bn0; bc1 = bn1; bc2 = bn2;
    }

    // ---- epilogue: C/D col=lane&31, row=(reg&3)+8*(reg>>2)+4*hi ----
    const float bv   = bias[0];
    const int   row0 = gy0 + rb * 32 + 4 * hi;
    const int   col0 = gx0 + cb * 128 + m;
    const bool  full = (gy0 + TBR <= OH) && (gx0 + TBC <= OW);

    const f32x16* accs[4] = {&acc0, &acc1, &acc2, &acc3};
#pragma unroll
    for (int g = 0; g < 4; ++g) {
        const f32x16 acc = *accs[g];
        const int col = col0 + g * 32;
        float* op = out + col;
        if (full) {
#pragma unroll
            for (int r = 0; r < 16; ++r) {
                int rr = row0 + (r & 3) + 8 * (r >> 2);
                op[(size_t)rr * OW] = acc[r] + bv;
            }
        } else if (col < OW) {
#pragma unroll
            for (int r = 0; r < 16; ++r) {
                int rr = row0 + (r & 3) + 8 * (r >> 2);
                if (rr < OH) op[(size_t)rr * OW] = acc[r] + bv;
            }
        }
    }
}

extern "C" void kernel_launch(void* const* d_in, const int* in_sizes, int n_in,
                              void* d_out, int out_size, void* d_ws, size_t ws_size,
                              hipStream_t stream) {
    const float* x  = (const float*)d_in[0];
    const float* w  = (const float*)d_in[1];
    const float* b  = (const float*)d_in[2];
    float* out = (float*)d_out;
    unsigned short* Bt = (unsigned short*)d_ws;

    build_B<<<96, 256, 0, stream>>>(w, Bt);

    dim3 grid((OW + TBC - 1) / TBC, (OH + TBR - 1) / TBR);  // 16 x 64
    conv_mfma32<<<grid, dim3(256), 0, stream>>>(x, Bt, b, out);
}